// Round 1
// baseline (233.743 us; speedup 1.0000x reference)
//
#include <hip/hip_runtime.h>
#include <stdint.h>

#define IN_F   4096
#define OUT_F  4096
#define M_TOT  512             // 4*128 rows
#define KT     (IN_F / 32)     // 128 global k-steps of 32
#define BN     64
#define BK     64
#define KSPLIT 4
#define KPB    (IN_F / KSPLIT) // 1024 K per block
#define NITER  (KPB / BK)      // 16 staging iterations

typedef unsigned short u16;
typedef __bf16 bf16x8 __attribute__((ext_vector_type(8)));
typedef float  f32x4  __attribute__((ext_vector_type(4)));

__device__ __forceinline__ u16 f2bf(float x) {
    unsigned u = __float_as_uint(x);
    u += 0x7FFFu + ((u >> 16) & 1u);   // round-to-nearest-even
    return (u16)(u >> 16);
}

// ---- pass 0: input fp32 -> bf16, MFMA-A-fragment order in workspace ----
// aws[((mt*KT + kt)*64 + lane)*8 + j] = in[mt*16 + (lane&15)][kt*32 + (lane>>4)*8 + j]
__global__ void pack_a_kernel(const float* __restrict__ in, u16* __restrict__ aws) {
    int t    = blockIdx.x * blockDim.x + threadIdx.x;  // 32*128*64 = 262144 threads
    int lane = t & 63;
    int kt   = (t >> 6) & (KT - 1);
    int mt   = t >> 13;
    int m = mt * 16 + (lane & 15);
    int k = kt * 32 + ((lane >> 4) << 3);
    const float* src = in + (size_t)m * IN_F + k;
    float4 a0 = *(const float4*)src;
    float4 a1 = *(const float4*)(src + 4);
    union { u16 u[8]; uint4 v; } pk;
    pk.u[0]=f2bf(a0.x); pk.u[1]=f2bf(a0.y); pk.u[2]=f2bf(a0.z); pk.u[3]=f2bf(a0.w);
    pk.u[4]=f2bf(a1.x); pk.u[5]=f2bf(a1.y); pk.u[6]=f2bf(a1.z); pk.u[7]=f2bf(a1.w);
    *(uint4*)(aws + (size_t)t * 8) = pk.v;
}

// ---- main: fused dequant + GEMM; 256 blocks (64 N-tiles x 4 K-splits), 512 thr ----
__global__ __launch_bounds__(512, 2) void qlinear_kernel(
    const u16*   __restrict__ aws,
    const int*   __restrict__ qw,
    const float* __restrict__ scales,
    const float* __restrict__ zeros,
    const float* __restrict__ outlier,
    const float* __restrict__ grad,
    float*       __restrict__ part)           // [KSPLIT][512][4096]
{
    __shared__ __align__(16) u16 Bsh[2][8 * 64 * 8];   // [buf][frag(ks*4+nf)][lane][8]

    const int tid  = threadIdx.x;
    const int lane = tid & 63;
    const int wv   = tid >> 6;                // 0..7, owns rows wv*64..wv*64+63

    const int nblk = blockIdx.x & 63;
    const int kblk = blockIdx.x >> 6;
    const int n0   = nblk * BN;
    const int k0   = kblk * KPB;

    // ---- staging role: thread covers weight row (n0+srow), 8-wide k-chunk ----
    const int srow = tid >> 3;                // 0..63
    const int schk = tid & 7;                 // 0..7
    const int orow = n0 + srow;
    const float sr = scales[orow];
    const float c0 = -zeros[orow] * sr;       // w = q*s + (o*g - z*s)
    const size_t sgoff = (size_t)orow * IN_F + k0 + schk * 8;
    const int sfrag = ((schk >> 2) << 2) + (srow >> 4);
    const int slane = (srow & 15) | ((schk & 3) << 4);
    u16* sdst0 = &Bsh[0][(sfrag * 64 + slane) * 8];
    u16* sdst1 = &Bsh[1][(sfrag * 64 + slane) * 8];

    // A fragment base: frag (mf, d) at abase + (mf*KT + d)*512, d = it*2+ks
    const u16* abase = aws + ((size_t)(wv * 4) * KT + (k0 >> 5)) * 512 + lane * 8;

    f32x4 acc[4][4] = {};

    int4 q0r, q1r; float4 o0r, o1r, g0r, g1r;

    auto load_tile = [&](int it) {
        size_t off = sgoff + (size_t)it * BK;
        q0r = *(const int4*)  (qw      + off);
        q1r = *(const int4*)  (qw      + off + 4);
        o0r = *(const float4*)(outlier + off);
        o1r = *(const float4*)(outlier + off + 4);
        g0r = *(const float4*)(grad    + off);
        g1r = *(const float4*)(grad    + off + 4);
    };
    auto store_tile = [&](u16* dst) {
        union { u16 u[8]; uint4 v; } pk;
        pk.u[0] = f2bf(fmaf((float)q0r.x, sr, fmaf(o0r.x, g0r.x, c0)));
        pk.u[1] = f2bf(fmaf((float)q0r.y, sr, fmaf(o0r.y, g0r.y, c0)));
        pk.u[2] = f2bf(fmaf((float)q0r.z, sr, fmaf(o0r.z, g0r.z, c0)));
        pk.u[3] = f2bf(fmaf((float)q0r.w, sr, fmaf(o0r.w, g0r.w, c0)));
        pk.u[4] = f2bf(fmaf((float)q1r.x, sr, fmaf(o1r.x, g1r.x, c0)));
        pk.u[5] = f2bf(fmaf((float)q1r.y, sr, fmaf(o1r.y, g1r.y, c0)));
        pk.u[6] = f2bf(fmaf((float)q1r.z, sr, fmaf(o1r.z, g1r.z, c0)));
        pk.u[7] = f2bf(fmaf((float)q1r.w, sr, fmaf(o1r.w, g1r.w, c0)));
        *(uint4*)dst = pk.v;
    };

    load_tile(0);
    store_tile(sdst0);
    load_tile(1);
    __syncthreads();

    for (int it = 0; it < NITER; ++it) {
        const u16* bbase = &Bsh[it & 1][0];

        bf16x8 af[2][4], bfr[2][4];
        #pragma unroll
        for (int ks = 0; ks < 2; ++ks)
            #pragma unroll
            for (int mf = 0; mf < 4; ++mf)
                af[ks][mf] = *(const bf16x8*)(abase + ((size_t)mf * KT + it * 2 + ks) * 512);
        #pragma unroll
        for (int ks = 0; ks < 2; ++ks)
            #pragma unroll
            for (int nf = 0; nf < 4; ++nf)
                bfr[ks][nf] = *(const bf16x8*)(bbase + ((ks * 4 + nf) * 64 + lane) * 8);

        #pragma unroll
        for (int ks = 0; ks < 2; ++ks)
            #pragma unroll
            for (int mf = 0; mf < 4; ++mf)
                #pragma unroll
                for (int nf = 0; nf < 4; ++nf)
                    acc[mf][nf] = __builtin_amdgcn_mfma_f32_16x16x32_bf16(
                        af[ks][mf], bfr[ks][nf], acc[mf][nf], 0, 0, 0);

        if (it + 1 < NITER) {
            store_tile((it + 1) & 1 ? sdst1 : sdst0);   // tile it+1 -> buf (it+1)&1
            if (it + 2 < NITER) load_tile(it + 2);
        }
        __syncthreads();
    }

    // ---- epilogue: write fp32 partials (C layout: row=(lane>>4)*4+r, col=lane&15) ----
    float* pout = part + (size_t)kblk * (M_TOT * OUT_F);
    const int cm0 = wv * 64 + ((lane >> 4) << 2);
    const int cn0 = n0 + (lane & 15);
    #pragma unroll
    for (int mf = 0; mf < 4; ++mf)
        #pragma unroll
        for (int nf = 0; nf < 4; ++nf) {
            float* op = pout + (size_t)(cm0 + mf * 16) * OUT_F + cn0 + nf * 16;
            #pragma unroll
            for (int r = 0; r < 4; ++r)
                op[(size_t)r * OUT_F] = acc[mf][nf][r];
        }
}

// ---- reduce: out = bias + sum_k partial[k] ----
__global__ void reduce_kernel(const float4* __restrict__ part,
                              const float4* __restrict__ bias,
                              float4* __restrict__ out) {
    int idx = blockIdx.x * blockDim.x + threadIdx.x;   // 524288
    float4 s = bias[idx & (OUT_F / 4 - 1)];
    const int STRIDE = M_TOT * OUT_F / 4;
    #pragma unroll
    for (int k = 0; k < KSPLIT; ++k) {
        float4 p = part[(size_t)k * STRIDE + idx];
        s.x += p.x; s.y += p.y; s.z += p.z; s.w += p.w;
    }
    out[idx] = s;
}

extern "C" void kernel_launch(void* const* d_in, const int* in_sizes, int n_in,
                              void* d_out, int out_size, void* d_ws, size_t ws_size,
                              hipStream_t stream) {
    const float* input   = (const float*)d_in[0];
    const int*   qweight = (const int*)  d_in[1];
    const float* scales  = (const float*)d_in[2];
    const float* zeros   = (const float*)d_in[3];
    const float* outlier = (const float*)d_in[4];
    const float* grad    = (const float*)d_in[5];
    const float* bias    = (const float*)d_in[6];
    float* out = (float*)d_out;

    u16*   aws  = (u16*)d_ws;                               // 4 MB
    float* part = (float*)((char*)d_ws + (4u << 20));       // 32 MB

    pack_a_kernel<<<(M_TOT * IN_F / 8) / 256, 256, 0, stream>>>(input, aws);
    qlinear_kernel<<<64 * KSPLIT, 512, 0, stream>>>(aws, qweight, scales, zeros,
                                                    outlier, grad, part);
    reduce_kernel<<<(M_TOT * OUT_F / 4) / 256, 256, 0, stream>>>(
        (const float4*)part, (const float4*)bias, (float4*)out);
}